// Round 8
// baseline (237.526 us; speedup 1.0000x reference)
//
#include <hip/hip_runtime.h>
#include <hip/hip_bf16.h>
#include <stdint.h>

#define B_ 1024
#define T_ 255
#define D_ 128

typedef float f32x4 __attribute__((ext_vector_type(4)));
typedef short s16x8 __attribute__((ext_vector_type(8)));
typedef unsigned u32x4 __attribute__((ext_vector_type(4)));

__device__ __forceinline__ unsigned pk2(float a, float b){
  __hip_bfloat162 h2 = __float22bfloat162_rn(make_float2(a, b));  // v_cvt_pk_bf16_f32
  union { __hip_bfloat162 h; unsigned u; } c; c.h = h2; return c.u;
}
__device__ __forceinline__ unsigned short bf1(float a){
  __hip_bfloat16 h = __float2bfloat16(a);
  union { __hip_bfloat16 h; unsigned short u; } c; c.h = h; return c.u;
}
__device__ __forceinline__ float sigm_f(float x){
  return __builtin_amdgcn_rcpf(1.f + __expf(-x));
}
__device__ __forceinline__ float tanh_f2(float x){
  return fmaf(-2.f, __builtin_amdgcn_rcpf(1.f + __expf(2.f * x)), 1.f);
}

// ---------------- Kernel 1: softmax(x_part) ; out_w = attn*x ; wx bf16 ----------
__global__ __launch_bounds__(512) void k_attn(const float* __restrict__ x,
    const float* __restrict__ Wa, float* __restrict__ out_w,
    uint2* __restrict__ wxq){
  extern __shared__ float4 xs4[];          // 8160 float4 = 130560 B
  __shared__ float wxs[256];
  __shared__ float part_s[16][128];
  __shared__ float red[128];
  __shared__ float attn_s[128];
  int tid = threadIdx.x, b = blockIdx.x;
  if (tid < T_) wxs[tid] = Wa[2 * D_ + tid];
  __syncthreads();
  const float4* xg = (const float4*)(x + (size_t)b * T_ * D_);
  float4 acc = {0.f, 0.f, 0.f, 0.f};
  for (int i = tid; i < 8160; i += 512){
    float4 v = xg[i];
    xs4[i] = v;
    float wt = wxs[i >> 5];
    acc.x += v.x * wt; acc.y += v.y * wt; acc.z += v.z * wt; acc.w += v.w * wt;
  }
  int d0 = (tid & 31) * 4, s = tid >> 5;
  *(float4*)&part_s[s][d0] = acc;
  __syncthreads();
  if (tid < 128){
    float v = 0.f;
    #pragma unroll
    for (int k = 0; k < 16; k++) v += part_s[k][tid];
    red[tid] = v; attn_s[tid] = v;
  }
  __syncthreads();
  for (int st = 64; st >= 1; st >>= 1){
    if (tid < st) red[tid] = fmaxf(red[tid], red[tid + st]);
    __syncthreads();
  }
  float mx = red[0];
  __syncthreads();
  float ev = 0.f;
  if (tid < 128){ ev = __expf(attn_s[tid] - mx); red[tid] = ev; }
  __syncthreads();
  for (int st = 64; st >= 1; st >>= 1){
    if (tid < st) red[tid] += red[tid + st];
    __syncthreads();
  }
  float sm = red[0];
  if (tid < 128) attn_s[tid] = ev / sm;
  __syncthreads();
  float4 at = *(const float4*)&attn_s[d0];
  float4* owg = (float4*)(out_w + (size_t)b * T_ * D_);
  for (int i = tid; i < 8160; i += 512){
    float4 v = xs4[i];
    float4 wv; wv.x = v.x*at.x; wv.y = v.y*at.y; wv.z = v.z*at.z; wv.w = v.w*at.w;
    owg[i] = wv;
    int t = i >> 5;
    uint2 q;
    q.x = pk2(wv.x, wv.y);
    q.y = pk2(wv.z, wv.w);
    wxq[((size_t)t * B_ + b) * 32 + (i & 31)] = q;   // [t][b][d] bf16 row-major
  }
}

// ---------------- Kernel 2: fused recurrence. 256 blocks x 4 rows x 512 thr -----
// Structure r7-proven. NEW: per-step barrier is lgkmcnt-only (no vmcnt(0) drain:
// out_e stores + wx prefetch loads stay in flight across steps); wx A-frags
// double-buffered 2 groups (8 steps) ahead.
__global__ __launch_bounds__(512, 2) void k_rnn(const float* __restrict__ W_ih,
    const float* __restrict__ W_hh, const float* __restrict__ b_ih,
    const float* __restrict__ b_hh, const unsigned short* __restrict__ wxb,
    float* __restrict__ out_e){
  __shared__ char hl[2048];      // h bf16 [buf][row 256B][slot 16B], slot^=(row&1)<<2
  __shared__ float4 g1l[2048];   // 32 KB f32 G1: [ts][br][d] -> (ts*4+br)*128+d
  int tid = threadIdx.x;
  int lane = tid & 63, w = tid >> 6;
  int l15 = lane & 15, lg = lane >> 4;
  int row0 = blockIdx.x << 2;
  int d = w * 16 + l15;
  int hr = l15 >> 2;             // h row this lane reads (x4 replication)

  // weight B-fragments [kt][gate], k = kt*32 + lg*8 + j
  s16x8 fih[4][4], fhh[4][4];
  float bias[4];
  #pragma unroll
  for (int g = 0; g < 4; g++){
    int n = g * 128 + w * 16 + l15;
    bias[g] = b_ih[n] + b_hh[n];
    #pragma unroll
    for (int kt = 0; kt < 4; kt++){
      const float4* p1 = (const float4*)(W_ih + n * D_ + kt * 32 + lg * 8);
      float4 a0 = p1[0], a1 = p1[1];
      u32x4 bv;
      bv[0] = pk2(a0.x, a0.y); bv[1] = pk2(a0.z, a0.w);
      bv[2] = pk2(a1.x, a1.y); bv[3] = pk2(a1.z, a1.w);
      fih[kt][g] = __builtin_bit_cast(s16x8, bv);
      const float4* p2 = (const float4*)(W_hh + n * D_ + kt * 32 + lg * 8);
      float4 c0v = p2[0], c1v = p2[1];
      u32x4 cv;
      cv[0] = pk2(c0v.x, c0v.y); cv[1] = pk2(c0v.z, c0v.w);
      cv[2] = pk2(c1v.x, c1v.y); cv[3] = pk2(c1v.z, c1v.w);
      fhh[kt][g] = __builtin_bit_cast(s16x8, cv);
    }
  }
  // h LDS addresses. Within-row 16B slot sigma = (k>>3) ^ ((row&1)<<2).
  unsigned rd_[4];
  #pragma unroll
  for (int kt = 0; kt < 4; kt++)
    rd_[kt] = (unsigned)(hr * 256 + (((kt << 2) + lg) ^ ((hr & 1) << 2)) * 16);
  unsigned wr_ = (unsigned)(lg * 256 + ((d >> 3) ^ ((lg & 1) << 2)) * 16 + (d & 7) * 2);

  float* op = out_e + (size_t)(row0 + lg) * T_ * D_ + d;
  float cst = 0.f;
  if (tid < 128) ((uint2*)hl)[tid] = make_uint2(0u, 0u);   // zero h buf0 (1 KB)

  // G1 float4 indices: write (ts=lg, br=r, d); read (ts=TS, br=lg, d). Wave-local.
  int gw0 = lg * 512 + d;
  int gr0 = lg * 128 + d;

  // fih A stream: lane reads wx[4*gp + (l15>>2)][row0 + (l15&3)][k-slice lg*8]
  const unsigned short* wpb = wxb + ((size_t)(l15 >> 2) * B_ + row0 + (l15 & 3)) * D_ + lg * 8;
  const size_t GSTRIDE = (size_t)4 * B_ * D_;               // 4 timesteps
  s16x8 AF0[4], AF1[4];
  #pragma unroll
  for (int kt = 0; kt < 4; kt++) AF0[kt] = *(const s16x8*)(wpb + kt * 32);
  #pragma unroll
  for (int kt = 0; kt < 4; kt++) AF1[kt] = *(const s16x8*)(wpb + GSTRIDE + kt * 32);
  __syncthreads();

  // lgkmcnt-only barrier: h LDS is the only cross-wave dependency; do NOT drain
  // vmcnt (out_e stores + wx prefetch stay outstanding across steps).
#define BAR() do {                                                                  \
    asm volatile("s_waitcnt lgkmcnt(0)" ::: "memory");                              \
    __builtin_amdgcn_s_barrier();                                                   \
  } while (0)

  // ---- batch-fih: 16 MFMA -> f32 G1 for 4 steps -> LDS (wave-local) ----
#define FIH_BATCH(AF) do {                                                          \
    f32x4 bi = {bias[0], bias[0], bias[0], bias[0]};                                \
    f32x4 bf = {bias[1], bias[1], bias[1], bias[1]};                                \
    f32x4 bg = {bias[2], bias[2], bias[2], bias[2]};                                \
    f32x4 bo = {bias[3], bias[3], bias[3], bias[3]};                                \
    _Pragma("unroll")                                                               \
    for (int kt = 0; kt < 4; kt++){                                                 \
      bi = __builtin_amdgcn_mfma_f32_16x16x32_bf16(AF[kt], fih[kt][0], bi,0,0,0);   \
      bf = __builtin_amdgcn_mfma_f32_16x16x32_bf16(AF[kt], fih[kt][1], bf,0,0,0);   \
      bg = __builtin_amdgcn_mfma_f32_16x16x32_bf16(AF[kt], fih[kt][2], bg,0,0,0);   \
      bo = __builtin_amdgcn_mfma_f32_16x16x32_bf16(AF[kt], fih[kt][3], bo,0,0,0);   \
    }                                                                               \
    _Pragma("unroll")                                                               \
    for (int r = 0; r < 4; r++)                                                     \
      g1l[gw0 + r * 128] = make_float4(bi[r], bf[r], bg[r], bo[r]);                 \
  } while (0)

  // ---- one recurrence step (TS compile-time 0..3; h buf parity = TS&1) ----
#define STEP(TS) do {                                                               \
    s16x8 aa[4];                                                                    \
    _Pragma("unroll")                                                               \
    for (int kt = 0; kt < 4; kt++)                                                  \
      aa[kt] = *(const s16x8*)(hl + rd_[kt] + ((TS) & 1) * 1024);                   \
    f32x4 a0 = {0.f,0.f,0.f,0.f}, a1 = a0, a2 = a0, a3 = a0;                        \
    _Pragma("unroll")                                                               \
    for (int kt = 0; kt < 4; kt++){                                                 \
      a0 = __builtin_amdgcn_mfma_f32_16x16x32_bf16(aa[kt], fhh[kt][0], a0,0,0,0);   \
      a1 = __builtin_amdgcn_mfma_f32_16x16x32_bf16(aa[kt], fhh[kt][1], a1,0,0,0);   \
      a2 = __builtin_amdgcn_mfma_f32_16x16x32_bf16(aa[kt], fhh[kt][2], a2,0,0,0);   \
      a3 = __builtin_amdgcn_mfma_f32_16x16x32_bf16(aa[kt], fhh[kt][3], a3,0,0,0);   \
    }                                                                               \
    float4 q = g1l[gr0 + (TS) * 512];                                               \
    float gi = q.x + a0[0], gf = q.y + a1[0];                                       \
    float gg = q.z + a2[0], go = q.w + a3[0];                                       \
    float cn = fmaf(sigm_f(gf), cst, sigm_f(gi) * tanh_f2(gg));                     \
    float hn = sigm_f(go) * tanh_f2(cn); cst = cn;                                  \
    *op = hn; op += D_;                                                             \
    *(unsigned short*)(hl + wr_ + (1 - ((TS) & 1)) * 1024) = bf1(hn);               \
    BAR();                                                                          \
  } while (0)

  for (int g = 0; g < 62; g += 2){
    FIH_BATCH(AF0);
    #pragma unroll
    for (int kt = 0; kt < 4; kt++)
      AF0[kt] = *(const s16x8*)(wpb + (size_t)(g + 2) * GSTRIDE + kt * 32);
    STEP(0); STEP(1); STEP(2); STEP(3);
    FIH_BATCH(AF1);
    #pragma unroll
    for (int kt = 0; kt < 4; kt++)
      AF1[kt] = *(const s16x8*)(wpb + (size_t)(g + 3) * GSTRIDE + kt * 32);
    STEP(0); STEP(1); STEP(2); STEP(3);
  }
  FIH_BATCH(AF0);                         // group 62: t = 248..251
  STEP(0); STEP(1); STEP(2); STEP(3);
  FIH_BATCH(AF1);                         // group 63: t = 252..254 (+zero pad)
  STEP(0); STEP(1); STEP(2);
#undef FIH_BATCH
#undef STEP
#undef BAR
}

extern "C" void kernel_launch(void* const* d_in, const int* in_sizes, int n_in,
                              void* d_out, int out_size, void* d_ws, size_t ws_size,
                              hipStream_t stream) {
  (void)in_sizes; (void)n_in; (void)out_size;
  const float* x    = (const float*)d_in[0];
  const float* Wa   = (const float*)d_in[1];
  // d_in[2] = ba : dead (softmax shift invariance); Wh/Wc parts of Wa also dead
  const float* W_ih = (const float*)d_in[3];
  const float* W_hh = (const float*)d_in[4];
  const float* b_ih = (const float*)d_in[5];
  const float* b_hh = (const float*)d_in[6];
  float* out_w = (float*)d_out;
  float* out_e = out_w + (size_t)B_ * T_ * D_;
  unsigned short* wxb = (unsigned short*)d_ws;   // [t][b][d] bf16; T+1 slots
  size_t need = (size_t)(T_ + 1) * B_ * D_ * 2;  // 67.1 MB (t=255 pad, zeroed)
  if (ws_size < need) return;

  // zero the t=255 pad slot (prefetched by the last group, rows never read)
  hipMemsetAsync((char*)d_ws + (size_t)T_ * B_ * D_ * 2, 0, (size_t)B_ * D_ * 2, stream);
  k_attn<<<B_, 512, 130560, stream>>>(x, Wa, out_w, (uint2*)wxb);
  k_rnn <<<256, 512, 0, stream>>>(W_ih, W_hh, b_ih, b_hh, wxb, out_e);
}